// Round 1
// baseline (12543.607 us; speedup 1.0000x reference)
//
#include <hip/hip_runtime.h>
#include <math.h>

#define B 32
#define T 800
#define DE 512
#define E 256
#define H 512
#define A 512
#define V 10000
#define G 2048
#define S 100
#define KX 1280   // gates K total (E + DE + H)
#define KY 1024   // logits K (H + DE)

// workspace offsets (floats)
#define OFF_ENCP   0
#define OFF_GP     (OFF_ENCP + B*T*A)       // 10*B*G
#define OFF_QP     (OFF_GP + 10*B*G)        // 8*B*A
#define OFF_QV     (OFF_QP + 8*B*A)         // B*A
#define OFF_XCAT   (OFF_QV + B*A)           // B*KX  [emb | ctx | dec_z]
#define OFF_YCAT   (OFF_XCAT + B*KX)        // B*KY  [dec_z | ctx]
#define OFF_DECC   (OFF_YCAT + B*KY)        // B*H
#define OFF_E      (OFF_DECC + B*H)         // B*T
#define OFF_CPART  (OFF_E + B*T)            // B*25*DE
#define OFF_LPART  (OFF_CPART + B*25*DE)    // 4*B*V

__device__ __forceinline__ float tanh_fast(float x) {
    float e = __expf(2.0f * x);
    return 1.0f - __fdividef(2.0f, e + 1.0f);
}

__global__ __launch_bounds__(256) void k_init(const float* emb, float* xcat, float* decc) {
    int b = blockIdx.x, t = threadIdx.x;
    xcat[b*KX + t] = emb[1*E + t];                 // BOS = 1
    #pragma unroll
    for (int i = 0; i < 4; i++) xcat[b*KX + E + i*256 + t] = 0.f;  // ctx + dec_z zero
    decc[b*H + t] = 0.f;
    decc[b*H + 256 + t] = 0.f;
}

// enc_proj[25600,512] = enc_pad[25600,512] @ W_enc[512,512]
__global__ __launch_bounds__(256) void k_encproj(const float* Ap, const float* Wenc, float* outp) {
    __shared__ float Ast[16][68];
    __shared__ float Bs[16][68];
    int rb = blockIdx.x, cb = blockIdx.y;
    int tid = threadIdx.x;
    int tx = tid & 15, ty = tid >> 4;
    float acc[4][4] = {};
    for (int kb = 0; kb < 32; kb++) {
        #pragma unroll
        for (int i = 0; i < 4; i++) {
            int idx = tid + i*256;
            int r = idx >> 4, k = idx & 15;
            Ast[k][r] = Ap[(rb*64 + r)*512 + kb*16 + k];
        }
        #pragma unroll
        for (int i = 0; i < 4; i++) {
            int idx = tid + i*256;
            int k = idx >> 6, c = idx & 63;
            Bs[k][c] = Wenc[(kb*16 + k)*512 + cb*64 + c];
        }
        __syncthreads();
        #pragma unroll
        for (int kk = 0; kk < 16; kk++) {
            float4 a4 = *(const float4*)&Ast[kk][ty*4];
            float4 b4 = *(const float4*)&Bs[kk][tx*4];
            const float av[4] = {a4.x, a4.y, a4.z, a4.w};
            const float bv[4] = {b4.x, b4.y, b4.z, b4.w};
            #pragma unroll
            for (int i = 0; i < 4; i++)
                #pragma unroll
                for (int j = 0; j < 4; j++)
                    acc[i][j] += av[i] * bv[j];
        }
        __syncthreads();
    }
    #pragma unroll
    for (int i = 0; i < 4; i++)
        #pragma unroll
        for (int j = 0; j < 4; j++)
            outp[(rb*64 + ty*4 + i)*512 + cb*64 + tx*4 + j] = acc[i][j];
}

// gates partials: gp[kc][b][j] = sum over k-chunk of x[b,k]*W(j,k)
__global__ __launch_bounds__(128) void k_gates(const float* Wih, const float* Whh,
                                               const float* xcat, float* gp) {
    int jt = blockIdx.x;   // 0..31 -> 64 j each
    int kc = blockIdx.y;   // 0..9  -> 128 k each
    __shared__ float xs[B][129];
    int tid = threadIdx.x;
    #pragma unroll
    for (int i = 0; i < 32; i++)
        xs[i][tid] = xcat[i*KX + kc*128 + tid];
    __syncthreads();
    int tj = tid & 15, tb = tid >> 4;
    int j0 = jt*64 + tj*4;
    int b0 = tb*4;
    const float* wbase; int krow, koff;
    if (kc < 6) { wbase = Wih; krow = 768; koff = kc*128; }
    else        { wbase = Whh; krow = 512; koff = (kc-6)*128; }
    float acc[4][4] = {};
    for (int kk = 0; kk < 128; kk += 4) {
        float4 wv[4];
        #pragma unroll
        for (int i = 0; i < 4; i++)
            wv[i] = *(const float4*)&wbase[(j0 + i)*krow + koff + kk];
        #pragma unroll
        for (int jj = 0; jj < 4; jj++) {
            float x0 = xs[b0+jj][kk+0], x1 = xs[b0+jj][kk+1];
            float x2 = xs[b0+jj][kk+2], x3 = xs[b0+jj][kk+3];
            #pragma unroll
            for (int i = 0; i < 4; i++)
                acc[i][jj] += wv[i].x*x0 + wv[i].y*x1 + wv[i].z*x2 + wv[i].w*x3;
        }
    }
    #pragma unroll
    for (int i = 0; i < 4; i++)
        #pragma unroll
        for (int jj = 0; jj < 4; jj++)
            gp[(kc*B + b0+jj)*G + j0 + i] = acc[i][jj];
}

__global__ __launch_bounds__(512) void k_lstm(const float* gp, const float* bih, const float* bhh,
                                              float* decc, float* ycat, float* xcat) {
    int b = blockIdx.x, h = threadIdx.x;
    float pi = bih[h]       + bhh[h];
    float pf = bih[H + h]   + bhh[H + h];
    float pg = bih[2*H + h] + bhh[2*H + h];
    float po = bih[3*H + h] + bhh[3*H + h];
    #pragma unroll
    for (int kc = 0; kc < 10; kc++) {
        const float* g = &gp[(kc*B + b)*G];
        pi += g[h]; pf += g[H+h]; pg += g[2*H+h]; po += g[3*H+h];
    }
    float ig = 1.f/(1.f + expf(-pi));
    float fg = 1.f/(1.f + expf(-pf));
    float gg = tanhf(pg);
    float og = 1.f/(1.f + expf(-po));
    float c = fg*decc[b*H + h] + ig*gg;
    decc[b*H + h] = c;
    float z = og*tanhf(c);
    ycat[b*KY + h] = z;
    xcat[b*KX + 768 + h] = z;
}

// q partials: qp[kc][b][a]
__global__ __launch_bounds__(128) void k_q(const float* Wdec, const float* ycat, float* qp) {
    int at = blockIdx.x;   // 0..7 -> 64 a
    int kc = blockIdx.y;   // 0..7 -> 64 h
    __shared__ float zs[B][65];
    int tid = threadIdx.x;
    #pragma unroll
    for (int i = 0; i < 16; i++) {
        int idx = tid + i*128;
        int r = idx >> 6, c = idx & 63;
        zs[r][c] = ycat[r*KY + kc*64 + c];
    }
    __syncthreads();
    int ta = tid & 15, tb = tid >> 4;
    int a0 = at*64 + ta*4;
    int b0 = tb*4;
    float acc[4][4] = {};
    for (int hh = 0; hh < 64; hh++) {
        float4 wv = *(const float4*)&Wdec[(kc*64 + hh)*A + a0];
        #pragma unroll
        for (int jj = 0; jj < 4; jj++) {
            float z = zs[b0+jj][hh];
            acc[0][jj] += wv.x*z; acc[1][jj] += wv.y*z;
            acc[2][jj] += wv.z*z; acc[3][jj] += wv.w*z;
        }
    }
    #pragma unroll
    for (int i = 0; i < 4; i++)
        #pragma unroll
        for (int jj = 0; jj < 4; jj++)
            qp[(kc*B + b0+jj)*A + a0 + i] = acc[i][jj];
}

__global__ __launch_bounds__(512) void k_qred(const float* qp, float* qv) {
    int b = blockIdx.x, a = threadIdx.x;
    float s = 0.f;
    #pragma unroll
    for (int kc = 0; kc < 8; kc++) s += qp[(kc*B + b)*A + a];
    qv[b*A + a] = s;
}

// e[b,t] = sum_a tanh(encp[b,t,a] + qv[b,a]) * v_att[a]
__global__ __launch_bounds__(256) void k_e(const float* encp, const float* qv, const float* vatt,
                                           const int* enclen, float* ebuf) {
    int b = blockIdx.x, tg = blockIdx.y;
    int len = enclen[b];
    if (tg*16 >= len) return;
    __shared__ float4 qv4[128];
    __shared__ float4 va4[128];
    int tid = threadIdx.x;
    float* qs = (float*)qv4;
    float* vs = (float*)va4;
    #pragma unroll
    for (int i = 0; i < 2; i++) {
        int a = tid + i*256;
        qs[a] = qv[b*A + a];
        vs[a] = vatt[a];
    }
    __syncthreads();
    int wid = tid >> 6, lane = tid & 63;
    const float4* ep4 = (const float4*)encp;
    #pragma unroll
    for (int tt = 0; tt < 4; tt++) {
        int t = tg*16 + wid*4 + tt;
        if (t >= len) continue;
        float acc = 0.f;
        #pragma unroll
        for (int i = 0; i < 2; i++) {
            int u = i*64 + lane;
            float4 ep = ep4[(b*T + t)*128 + u];
            float4 q4 = qv4[u], vv = va4[u];
            acc += tanh_fast(ep.x + q4.x)*vv.x;
            acc += tanh_fast(ep.y + q4.y)*vv.y;
            acc += tanh_fast(ep.z + q4.z)*vv.z;
            acc += tanh_fast(ep.w + q4.w)*vv.w;
        }
        #pragma unroll
        for (int m = 32; m >= 1; m >>= 1) acc += __shfl_xor(acc, m, 64);
        if (lane == 0) ebuf[b*T + t] = acc;
    }
}

__global__ __launch_bounds__(256) void k_softmax(const float* ebuf, const int* enclen,
                                                 float* outp, int s) {
    int b = blockIdx.x, tid = threadIdx.x;
    int len = enclen[b];
    __shared__ float red[256];
    float m = -3.0e38f;
    for (int t = tid; t < len; t += 256) m = fmaxf(m, ebuf[b*T + t]);
    red[tid] = m; __syncthreads();
    for (int st = 128; st >= 1; st >>= 1) {
        if (tid < st) red[tid] = fmaxf(red[tid], red[tid+st]);
        __syncthreads();
    }
    float M = red[0]; __syncthreads();
    float sum = 0.f;
    for (int t = tid; t < len; t += 256) sum += expf(ebuf[b*T + t] - M);
    red[tid] = sum; __syncthreads();
    for (int st = 128; st >= 1; st >>= 1) {
        if (tid < st) red[tid] += red[tid+st];
        __syncthreads();
    }
    float inv = 1.f / red[0];
    float* wrow = outp + 2*B*S + (size_t)(b*S + s)*T;
    for (int t = tid; t < T; t += 256)
        wrow[t] = (t < len) ? expf(ebuf[b*T + t] - M)*inv : 0.f;
}

// context partials over t-groups of 32
__global__ __launch_bounds__(512) void k_ctxpart(const float* encpad, const float* outp,
                                                 float* cpart, int s) {
    int b = blockIdx.x, g = blockIdx.y;
    __shared__ float wls[32];
    int tid = threadIdx.x;
    const float* wrow = outp + 2*B*S + (size_t)(b*S + s)*T + g*32;
    if (tid < 32) wls[tid] = wrow[tid];
    __syncthreads();
    float wsum = 0.f;
    #pragma unroll
    for (int i = 0; i < 32; i++) wsum += wls[i];
    float acc = 0.f;
    if (wsum != 0.f) {
        #pragma unroll 8
        for (int i = 0; i < 32; i++)
            acc += wls[i] * encpad[(size_t)(b*T + g*32 + i)*DE + tid];
    }
    cpart[(b*25 + g)*DE + tid] = acc;
}

__global__ __launch_bounds__(512) void k_ctxred(const float* cpart, float* ycat, float* xcat) {
    int b = blockIdx.x, d = threadIdx.x;
    float s = 0.f;
    #pragma unroll
    for (int g = 0; g < 25; g++) s += cpart[(b*25 + g)*DE + d];
    ycat[b*KY + H + d] = s;
    xcat[b*KX + E + d] = s;
}

// logits partials lp[kc][b][v], kc over 4 chunks of 256 k
__global__ __launch_bounds__(128) void k_logits(const float* Wout, const float* ycat, float* lp) {
    int vt = blockIdx.x;   // 0..156
    int kc = blockIdx.y;   // 0..3
    __shared__ float ys[B][257];
    int tid = threadIdx.x;
    #pragma unroll 8
    for (int i = 0; i < 64; i++) {
        int idx = tid + i*128;
        int r = idx >> 8, c = idx & 255;
        ys[r][c] = ycat[r*KY + kc*256 + c];
    }
    __syncthreads();
    int tv = tid & 15, tb = tid >> 4;
    int v0 = vt*64 + tv*4;
    int b0 = tb*4;
    float acc[4][4] = {};
    for (int kk = 0; kk < 256; kk += 4) {
        float4 wv[4];
        #pragma unroll
        for (int i = 0; i < 4; i++) {
            int v = v0 + i;
            wv[i] = (v < V) ? *(const float4*)&Wout[(size_t)v*KY + kc*256 + kk]
                            : make_float4(0.f, 0.f, 0.f, 0.f);
        }
        #pragma unroll
        for (int jj = 0; jj < 4; jj++) {
            float y0 = ys[b0+jj][kk+0], y1 = ys[b0+jj][kk+1];
            float y2 = ys[b0+jj][kk+2], y3 = ys[b0+jj][kk+3];
            #pragma unroll
            for (int i = 0; i < 4; i++)
                acc[i][jj] += wv[i].x*y0 + wv[i].y*y1 + wv[i].z*y2 + wv[i].w*y3;
        }
    }
    #pragma unroll
    for (int i = 0; i < 4; i++) {
        int v = v0 + i;
        if (v < V) {
            #pragma unroll
            for (int jj = 0; jj < 4; jj++)
                lp[((size_t)kc*B + b0+jj)*V + v] = acc[i][jj];
        }
    }
}

__global__ __launch_bounds__(256) void k_argmax(const float* lp, const float* bout, const float* emb,
                                                float* outp, float* xcat, int s) {
    int b = blockIdx.x, tid = threadIdx.x;
    __shared__ float sval[256];
    __shared__ int sidx[256];
    float lv[40];
    float lmax = -3.0e38f; int lidx = 0x7fffffff;
    #pragma unroll
    for (int it = 0; it < 40; it++) {
        int v = it*256 + tid;
        float x = -3.0e38f;
        if (v < V) {
            x = bout[v];
            #pragma unroll
            for (int kc = 0; kc < 4; kc++) x += lp[((size_t)kc*B + b)*V + v];
        }
        lv[it] = x;
        if (x > lmax) { lmax = x; lidx = v; }
    }
    sval[tid] = lmax; sidx[tid] = lidx; __syncthreads();
    for (int st = 128; st >= 1; st >>= 1) {
        if (tid < st) {
            float ov = sval[tid+st]; int oi = sidx[tid+st];
            if (ov > sval[tid] || (ov == sval[tid] && oi < sidx[tid])) {
                sval[tid] = ov; sidx[tid] = oi;
            }
        }
        __syncthreads();
    }
    float M = sval[0]; int am = sidx[0];
    __syncthreads();
    float sum = 0.f;
    #pragma unroll
    for (int it = 0; it < 40; it++) sum += expf(lv[it] - M);
    sval[tid] = sum; __syncthreads();
    for (int st = 128; st >= 1; st >>= 1) {
        if (tid < st) sval[tid] += sval[tid+st];
        __syncthreads();
    }
    if (tid == 0) {
        outp[b*S + s] = -logf(sval[0]);           // ys_log_probs
        outp[B*S + b*S + s] = (float)am;          // preds (as float)
    }
    xcat[b*KX + tid] = emb[(size_t)am*E + tid];   // next-step embedding
}

extern "C" void kernel_launch(void* const* d_in, const int* in_sizes, int n_in,
                              void* d_out, int out_size, void* d_ws, size_t ws_size,
                              hipStream_t stream) {
    const float* encpad = (const float*)d_in[0];
    const float* emb    = (const float*)d_in[1];
    const float* Wih    = (const float*)d_in[2];
    const float* Whh    = (const float*)d_in[3];
    const float* bih    = (const float*)d_in[4];
    const float* bhh    = (const float*)d_in[5];
    const float* Wenc   = (const float*)d_in[6];
    const float* Wdec   = (const float*)d_in[7];
    const float* vatt   = (const float*)d_in[8];
    const float* Wout   = (const float*)d_in[9];
    const float* bout   = (const float*)d_in[10];
    const int*   enclen = (const int*)d_in[11];
    float* outp = (float*)d_out;
    float* ws   = (float*)d_ws;

    float* encp  = ws + OFF_ENCP;
    float* gp    = ws + OFF_GP;
    float* qp    = ws + OFF_QP;
    float* qv    = ws + OFF_QV;
    float* xcat  = ws + OFF_XCAT;
    float* ycat  = ws + OFF_YCAT;
    float* decc  = ws + OFF_DECC;
    float* ebuf  = ws + OFF_E;
    float* cpart = ws + OFF_CPART;
    float* lp    = ws + OFF_LPART;

    k_init<<<B, 256, 0, stream>>>(emb, xcat, decc);
    k_encproj<<<dim3(400, 8), 256, 0, stream>>>(encpad, Wenc, encp);
    for (int s = 0; s < S; s++) {
        k_gates<<<dim3(32, 10), 128, 0, stream>>>(Wih, Whh, xcat, gp);
        k_lstm<<<B, 512, 0, stream>>>(gp, bih, bhh, decc, ycat, xcat);
        k_q<<<dim3(8, 8), 128, 0, stream>>>(Wdec, ycat, qp);
        k_qred<<<B, 512, 0, stream>>>(qp, qv);
        k_e<<<dim3(B, 50), 256, 0, stream>>>(encp, qv, vatt, enclen, ebuf);
        k_softmax<<<B, 256, 0, stream>>>(ebuf, enclen, outp, s);
        k_ctxpart<<<dim3(B, 25), 512, 0, stream>>>(encpad, outp, cpart, s);
        k_ctxred<<<B, 512, 0, stream>>>(cpart, ycat, xcat);
        k_logits<<<dim3(157, 4), 128, 0, stream>>>(Wout, ycat, lp);
        k_argmax<<<B, 256, 0, stream>>>(lp, bout, emb, outp, xcat, s);
    }
}